// Round 1
// baseline (2239.125 us; speedup 1.0000x reference)
//
#include <hip/hip_runtime.h>

#define N_NODES 100000
#define N_EDGES 200000
#define D_NODE  128
#define D_EDGE  16
#define N_REL   3

// ---------------------------------------------------------------------------
// Pass 1: scatter-accumulate raw features per relation.
//   S[r][dst] += x[src]           (128 f32)
//   E[r][dst] += edge_attr[r][e]  (16 f32)
// 8 edges per 256-thread block, 32 lanes per edge, float4 per lane.
// ---------------------------------------------------------------------------
__global__ __launch_bounds__(256) void scatter_kernel(
    const float* __restrict__ x,
    const float* __restrict__ edge_attr,
    const int*   __restrict__ edge_index,
    float* __restrict__ S,
    float* __restrict__ Eagg)
{
    const int  slot = threadIdx.x >> 5;      // 0..7
    const int  lane = threadIdx.x & 31;      // 0..31
    const long long eid = (long long)blockIdx.x * 8 + slot;
    if (eid >= (long long)N_REL * N_EDGES) return;
    const int r = (int)(eid / N_EDGES);
    const int e = (int)(eid - (long long)r * N_EDGES);
    const size_t ebase = (size_t)r * N_EDGES + e;
    const int src = edge_index[ebase * 2 + 0];
    const int dst = edge_index[ebase * 2 + 1];

    // gather x row (512B contiguous, coalesced within the 32-lane group)
    const float4 xv = ((const float4*)(x + (size_t)src * D_NODE))[lane];
    float* Srow = S + ((size_t)r * N_NODES + dst) * D_NODE + lane * 4;
    unsafeAtomicAdd(Srow + 0, xv.x);
    unsafeAtomicAdd(Srow + 1, xv.y);
    unsafeAtomicAdd(Srow + 2, xv.z);
    unsafeAtomicAdd(Srow + 3, xv.w);

    if (lane < 4) {
        const float4 ev = ((const float4*)(edge_attr + ebase * D_EDGE))[lane];
        float* Erow = Eagg + ((size_t)r * N_NODES + dst) * D_EDGE + lane * 4;
        unsafeAtomicAdd(Erow + 0, ev.x);
        unsafeAtomicAdd(Erow + 1, ev.y);
        unsafeAtomicAdd(Erow + 2, ev.z);
        unsafeAtomicAdd(Erow + 3, ev.w);
    }
}

// ---------------------------------------------------------------------------
// Pass 2: fused GEMM over concatenated K:
//   out[n,:] = relu( x@W_self + sum_r S_r@W_r + sum_r E_r@We_r + b )
// Tile: 64 rows x 128 cols per block (256 threads), BK=16.
// Thread micro-tile: 8 rows (stride 8) x 4 cols (float4).
// ---------------------------------------------------------------------------
template<int KSEG>
__device__ __forceinline__ void gemm_seg(
    const float* __restrict__ A, int lda, const float* __restrict__ W,
    int m0, int tid, int ty, int tx,
    float (&acc)[8][4], float (&As)[16][65], float (&Ws)[16][128])
{
    for (int k0 = 0; k0 < KSEG; k0 += 16) {
        // stage A tile (64 rows x 16 k), transposed into As[k][m]
        {
            const int row = tid >> 2;            // 0..63
            const int kv  = (tid & 3) << 2;      // 0,4,8,12
            const int gr  = m0 + row;
            float4 v = make_float4(0.f, 0.f, 0.f, 0.f);
            if (gr < N_NODES)
                v = *(const float4*)(A + (size_t)gr * lda + k0 + kv);
            As[kv + 0][row] = v.x;
            As[kv + 1][row] = v.y;
            As[kv + 2][row] = v.z;
            As[kv + 3][row] = v.w;
        }
        // stage W tile (16 k x 128 cols)
        {
            const int kk = tid >> 4;             // 0..15
            const int c0 = (tid & 15) << 3;      // 0..120 step 8
            const float* wp = W + (size_t)(k0 + kk) * 128 + c0;
            const float4 w0 = *(const float4*)(wp);
            const float4 w1 = *(const float4*)(wp + 4);
            *(float4*)&Ws[kk][c0]     = w0;
            *(float4*)&Ws[kk][c0 + 4] = w1;
        }
        __syncthreads();
        #pragma unroll
        for (int k = 0; k < 16; ++k) {
            float a[8];
            #pragma unroll
            for (int i = 0; i < 8; ++i) a[i] = As[k][(i << 3) + ty];
            const float4 w = *(const float4*)&Ws[k][tx << 2];
            #pragma unroll
            for (int i = 0; i < 8; ++i) {
                acc[i][0] = fmaf(a[i], w.x, acc[i][0]);
                acc[i][1] = fmaf(a[i], w.y, acc[i][1]);
                acc[i][2] = fmaf(a[i], w.z, acc[i][2]);
                acc[i][3] = fmaf(a[i], w.w, acc[i][3]);
            }
        }
        __syncthreads();
    }
}

__global__ __launch_bounds__(256) void fused_gemm_kernel(
    const float* __restrict__ x,
    const float* __restrict__ S,
    const float* __restrict__ Eg,
    const float* __restrict__ W_rel,
    const float* __restrict__ We_rel,
    const float* __restrict__ W_self,
    const float* __restrict__ b,
    float* __restrict__ out)
{
    __shared__ float As[16][65];    // +1 pad
    __shared__ float Ws[16][128];
    const int tid = threadIdx.x;
    const int m0  = blockIdx.x * 64;
    const int ty  = tid >> 5;       // 0..7  (row group)
    const int tx  = tid & 31;       // 0..31 (col group)

    float acc[8][4];
    #pragma unroll
    for (int i = 0; i < 8; ++i)
        #pragma unroll
        for (int j = 0; j < 4; ++j) acc[i][j] = 0.f;

    // self-loop segment
    gemm_seg<128>(x, D_NODE, W_self, m0, tid, ty, tx, acc, As, Ws);
    // per-relation node-feature segments
    #pragma unroll
    for (int r = 0; r < N_REL; ++r)
        gemm_seg<128>(S + (size_t)r * N_NODES * D_NODE, D_NODE,
                      W_rel + (size_t)r * D_NODE * D_NODE,
                      m0, tid, ty, tx, acc, As, Ws);
    // per-relation edge-attr segments
    #pragma unroll
    for (int r = 0; r < N_REL; ++r)
        gemm_seg<16>(Eg + (size_t)r * N_NODES * D_EDGE, D_EDGE,
                     We_rel + (size_t)r * D_EDGE * D_NODE,
                     m0, tid, ty, tx, acc, As, Ws);

    // epilogue: + bias, relu, store
    const float4 bias = *(const float4*)(b + (tx << 2));
    #pragma unroll
    for (int i = 0; i < 8; ++i) {
        const int m = m0 + (i << 3) + ty;
        if (m < N_NODES) {
            float4 o;
            o.x = fmaxf(acc[i][0] + bias.x, 0.f);
            o.y = fmaxf(acc[i][1] + bias.y, 0.f);
            o.z = fmaxf(acc[i][2] + bias.z, 0.f);
            o.w = fmaxf(acc[i][3] + bias.w, 0.f);
            *(float4*)(out + (size_t)m * D_NODE + (tx << 2)) = o;
        }
    }
}

extern "C" void kernel_launch(void* const* d_in, const int* in_sizes, int n_in,
                              void* d_out, int out_size, void* d_ws, size_t ws_size,
                              hipStream_t stream)
{
    const float* x         = (const float*)d_in[0];
    const float* edge_attr = (const float*)d_in[1];
    const float* W_rel     = (const float*)d_in[2];
    const float* We_rel    = (const float*)d_in[3];
    const float* W_self    = (const float*)d_in[4];
    const float* b         = (const float*)d_in[5];
    const int*   edge_index= (const int*)d_in[6];
    float* out = (float*)d_out;

    float* S    = (float*)d_ws;                                   // 3*100000*128 f32
    float* Eagg = S + (size_t)N_REL * N_NODES * D_NODE;           // 3*100000*16  f32
    const size_t zero_bytes =
        ((size_t)N_REL * N_NODES * D_NODE + (size_t)N_REL * N_NODES * D_EDGE) * sizeof(float);

    hipMemsetAsync(d_ws, 0, zero_bytes, stream);

    const int n_edge_total = N_REL * N_EDGES;
    scatter_kernel<<<(n_edge_total + 7) / 8, 256, 0, stream>>>(
        x, edge_attr, edge_index, S, Eagg);

    fused_gemm_kernel<<<(N_NODES + 63) / 64, 256, 0, stream>>>(
        x, S, Eagg, W_rel, We_rel, W_self, b, out);
}

// Round 2
// 674.585 us; speedup vs baseline: 3.3193x; 3.3193x over previous
//
#include <hip/hip_runtime.h>

#define NN 100000
#define NE 200000
#define DN 128
#define DE 16
#define NR 3

typedef __attribute__((ext_vector_type(8))) short short8;
typedef __attribute__((ext_vector_type(4))) float f32x4;

__device__ __forceinline__ unsigned short f2bf(float f) {
    unsigned int u = __float_as_uint(f);
    u = (u + 0x7fffu + ((u >> 16) & 1u)) >> 16;   // RNE
    return (unsigned short)u;
}

// ---------------------------------------------------------------------------
// xb = bf16(x), 4 elems/thread
// ---------------------------------------------------------------------------
__global__ __launch_bounds__(256) void conv_x_kernel(
    const float* __restrict__ x, unsigned short* __restrict__ xb)
{
    const int i = blockIdx.x * 256 + threadIdx.x;   // float4 index, 3.2M total
    if (i < NN * DN / 4) {
        float4 v = ((const float4*)x)[i];
        ushort4 o;
        o.x = f2bf(v.x); o.y = f2bf(v.y); o.z = f2bf(v.z); o.w = f2bf(v.w);
        ((ushort4*)xb)[i] = o;
    }
}

// ---------------------------------------------------------------------------
// Wt[m][n][k] = bf16(W_m[k][n]) — transposed to n-major so MFMA B-fragments
// (lane needs 8 consecutive k for fixed n) are contiguous. m=0:W_self, 1..3:W_rel
// ---------------------------------------------------------------------------
__global__ __launch_bounds__(256) void conv_w_kernel(
    const float* __restrict__ W_self, const float* __restrict__ W_rel,
    unsigned short* __restrict__ Wt)
{
    const int id = blockIdx.x * 256 + threadIdx.x;  // 65536
    const int m = id >> 14, rem = id & 16383;
    const int k = rem >> 7, n = rem & 127;          // read coalesced over n
    const float* src = (m == 0) ? W_self : (W_rel + (size_t)(m - 1) * 16384);
    Wt[m * 16384 + n * 128 + k] = f2bf(src[k * 128 + n]);
}

// ---------------------------------------------------------------------------
// One MFMA GEMM for 4 weight matrices: C_m = xb @ W_m  (K=128, single stage)
//   m=0 -> agg (fp32, becomes the accumulator init = x@W_self)
//   m>0 -> y[m-1] (bf16, gathered by scatter)
// Block: 256 thr (4 waves) = 64 rows x 128 cols. Wave w: rows [16w,16w+16).
// ---------------------------------------------------------------------------
__global__ __launch_bounds__(256) void gemm_kernel(
    const unsigned short* __restrict__ xb,
    const unsigned short* __restrict__ Wt,
    float* __restrict__ agg,
    unsigned short* __restrict__ y)
{
    __shared__ unsigned short As[64 * 136];    // pad 128->136 (2-way max, free)
    __shared__ unsigned short Bs[128 * 136];
    const int tid = threadIdx.x;
    const int m0  = blockIdx.x * 64;
    const int mat = blockIdx.y;

    // stage A: 64 rows x 128 bf16, 16B chunks
    #pragma unroll
    for (int i = 0; i < 4; ++i) {
        int c = tid + i * 256;             // 0..1023
        int row = c >> 4, ch = c & 15;
        int gr = m0 + row;
        uint4 v = make_uint4(0u, 0u, 0u, 0u);
        if (gr < NN) v = *(const uint4*)(xb + (size_t)gr * 128 + ch * 8);
        *(uint4*)&As[row * 136 + ch * 8] = v;
    }
    // stage B: this matrix, 128 n-rows x 128 k
    {
        const unsigned short* wsrc = Wt + (size_t)mat * 16384;
        #pragma unroll
        for (int i = 0; i < 8; ++i) {
            int c = tid + i * 256;         // 0..2047
            int n = c >> 4, ch = c & 15;
            *(uint4*)&Bs[n * 136 + ch * 8] = *(const uint4*)(wsrc + n * 128 + ch * 8);
        }
    }
    __syncthreads();

    const int wave = tid >> 6;
    const int lane = tid & 63;
    const int lm = lane & 15;    // A row / B col(n) / C col
    const int lq = lane >> 4;    // quad -> k-group of 8 / C row group

    short8 af[4];
    #pragma unroll
    for (int ks = 0; ks < 4; ++ks)
        af[ks] = *(const short8*)&As[(wave * 16 + lm) * 136 + ks * 32 + lq * 8];

    f32x4 acc[8];
    #pragma unroll
    for (int n = 0; n < 8; ++n) acc[n] = (f32x4){0.f, 0.f, 0.f, 0.f};

    #pragma unroll
    for (int n = 0; n < 8; ++n) {
        #pragma unroll
        for (int ks = 0; ks < 4; ++ks) {
            short8 bf = *(const short8*)&Bs[(n * 16 + lm) * 136 + ks * 32 + lq * 8];
            acc[n] = __builtin_amdgcn_mfma_f32_16x16x32_bf16(af[ks], bf, acc[n], 0, 0, 0);
        }
    }

    // epilogue: C[row=(16w + 4*lq + j)][col=16n + lm]
    if (mat == 0) {
        #pragma unroll
        for (int n = 0; n < 8; ++n)
            #pragma unroll
            for (int j = 0; j < 4; ++j) {
                int gr = m0 + wave * 16 + lq * 4 + j;
                if (gr < NN) agg[(size_t)gr * 128 + n * 16 + lm] = acc[n][j];
            }
    } else {
        unsigned short* yp = y + (size_t)(mat - 1) * NN * 128;
        #pragma unroll
        for (int n = 0; n < 8; ++n)
            #pragma unroll
            for (int j = 0; j < 4; ++j) {
                int gr = m0 + wave * 16 + lq * 4 + j;
                if (gr < NN) yp[(size_t)gr * 128 + n * 16 + lm] = f2bf(acc[n][j]);
            }
    }
}

// ---------------------------------------------------------------------------
// Scatter: for each edge (r,e): agg[dst] += y_r[src] + edge_attr[r,e] @ We_r
// One 64-lane wave per edge, 2 output cols per lane; We_r columns cached in
// registers (32 f32/lane). 16 edges per block (4 waves x 4 iters); block's
// relation is uniform (16 | NE).
// ---------------------------------------------------------------------------
__global__ __launch_bounds__(256) void scatter_kernel(
    const unsigned short* __restrict__ y,    // [3][NN][128] bf16
    const float* __restrict__ edge_attr,     // [3][NE][16]
    const float* __restrict__ We,            // [3][16][128] fp32
    const int*   __restrict__ edge_index,    // [3][NE][2]
    float* __restrict__ agg)
{
    __shared__ float WeS[16 * 128];
    const int tid  = threadIdx.x;
    const int base = blockIdx.x * 16;        // first edge id (global over 600k)
    const int r    = base / NE;

    {   // stage We_r (coalesced)
        const float* w = We + (size_t)r * 16 * 128;
        #pragma unroll
        for (int i = 0; i < 2; ++i) {
            int c = (tid + i * 256) * 4;
            *(float4*)&WeS[c] = *(const float4*)(w + c);
        }
    }
    __syncthreads();

    const int lane = tid & 63;
    const int wave = tid >> 6;
    float w0[16], w1[16];
    #pragma unroll
    for (int j = 0; j < 16; ++j) {
        w0[j] = WeS[j * 128 + 2 * lane];
        w1[j] = WeS[j * 128 + 2 * lane + 1];
    }

    const unsigned short* yr = y + (size_t)r * NN * 128;
    #pragma unroll
    for (int it = 0; it < 4; ++it) {
        const int eid = base + it * 4 + wave;           // same r for whole block
        const size_t eb = (size_t)eid;                  // == r*NE + e
        const int src = edge_index[eb * 2 + 0];
        const int dst = edge_index[eb * 2 + 1];

        // gather y_r[src], 2 bf16 per lane
        const unsigned int p = *(const unsigned int*)(yr + (size_t)src * 128 + 2 * lane);
        float m0v = __uint_as_float(p << 16);
        float m1v = __uint_as_float(p & 0xffff0000u);

        // edge_attr part: 16-wide dot with register-cached We columns
        const float4* ap = (const float4*)(edge_attr + eb * 16);
        float4 a0 = ap[0], a1 = ap[1], a2 = ap[2], a3 = ap[3];
        const float av[16] = {a0.x,a0.y,a0.z,a0.w, a1.x,a1.y,a1.z,a1.w,
                              a2.x,a2.y,a2.z,a2.w, a3.x,a3.y,a3.z,a3.w};
        #pragma unroll
        for (int j = 0; j < 16; ++j) {
            m0v = fmaf(av[j], w0[j], m0v);
            m1v = fmaf(av[j], w1[j], m1v);
        }

        float* dp = agg + (size_t)dst * 128 + 2 * lane;
        unsafeAtomicAdd(dp + 0, m0v);
        unsafeAtomicAdd(dp + 1, m1v);
    }
}

// ---------------------------------------------------------------------------
// out = relu(agg + b)
// ---------------------------------------------------------------------------
__global__ __launch_bounds__(256) void relu_bias_kernel(
    const float* __restrict__ agg, const float* __restrict__ b,
    float* __restrict__ out)
{
    const int total = NN * DN / 4;               // float4 units
    for (int i = blockIdx.x * 256 + threadIdx.x; i < total; i += gridDim.x * 256) {
        float4 v = ((const float4*)agg)[i];
        float4 bb = ((const float4*)b)[i & 31];
        float4 o;
        o.x = fmaxf(v.x + bb.x, 0.f);
        o.y = fmaxf(v.y + bb.y, 0.f);
        o.z = fmaxf(v.z + bb.z, 0.f);
        o.w = fmaxf(v.w + bb.w, 0.f);
        ((float4*)out)[i] = o;
    }
}

extern "C" void kernel_launch(void* const* d_in, const int* in_sizes, int n_in,
                              void* d_out, int out_size, void* d_ws, size_t ws_size,
                              hipStream_t stream)
{
    const float* x         = (const float*)d_in[0];
    const float* edge_attr = (const float*)d_in[1];
    const float* W_rel     = (const float*)d_in[2];
    const float* We_rel    = (const float*)d_in[3];
    const float* W_self    = (const float*)d_in[4];
    const float* b         = (const float*)d_in[5];
    const int*   edge_index= (const int*)d_in[6];
    float* out = (float*)d_out;

    // ws layout (bytes): agg 51.2e6 | xb 25.6e6 | y 76.8e6 | Wt 131072
    char* wsb = (char*)d_ws;
    float*          agg = (float*)wsb;
    unsigned short* xb  = (unsigned short*)(wsb + 51200000);
    unsigned short* y   = (unsigned short*)(wsb + 76800000);
    unsigned short* Wt  = (unsigned short*)(wsb + 153600000);

    conv_x_kernel<<<NN * DN / 4 / 256, 256, 0, stream>>>(x, xb);
    conv_w_kernel<<<256, 256, 0, stream>>>(W_self, W_rel, Wt);

    dim3 ggrid((NN + 63) / 64, 4);
    gemm_kernel<<<ggrid, 256, 0, stream>>>(xb, Wt, agg, y);

    scatter_kernel<<<NR * NE / 16, 256, 0, stream>>>(y, edge_attr, We_rel,
                                                     edge_index, agg);

    relu_bias_kernel<<<2048, 256, 0, stream>>>(agg, b, out);
}

// Round 3
// 435.519 us; speedup vs baseline: 5.1413x; 1.5489x over previous
//
#include <hip/hip_runtime.h>

#define NN 100000
#define NE 200000
#define DN 128
#define DE 16
#define NR 3
#define NKEY (NR * NN)          // 300000 (r,dst) buckets
#define NEDGE (NR * NE)         // 600000
#define NB1 293                 // scan1 blocks: 1024 elems each >= NKEY

typedef __attribute__((ext_vector_type(8))) short short8;
typedef __attribute__((ext_vector_type(4))) float f32x4;

__device__ __forceinline__ unsigned short f2bf(float f) {
    unsigned int u = __float_as_uint(f);
    u = (u + 0x7fffu + ((u >> 16) & 1u)) >> 16;   // RNE
    return (unsigned short)u;
}

// ---------------------------------------------------------------------------
// xb = bf16(x)
// ---------------------------------------------------------------------------
__global__ __launch_bounds__(256) void conv_x_kernel(
    const float* __restrict__ x, unsigned short* __restrict__ xb)
{
    const int i = blockIdx.x * 256 + threadIdx.x;   // float4 index, 3.2M total
    if (i < NN * DN / 4) {
        float4 v = ((const float4*)x)[i];
        ushort4 o;
        o.x = f2bf(v.x); o.y = f2bf(v.y); o.z = f2bf(v.z); o.w = f2bf(v.w);
        ((ushort4*)xb)[i] = o;
    }
}

// ---------------------------------------------------------------------------
// Wt[m][n][k] = bf16(W_m[k][n]) (n-major for MFMA B-fragments). m=0 self, 1..3 rel
// ---------------------------------------------------------------------------
__global__ __launch_bounds__(256) void conv_w_kernel(
    const float* __restrict__ W_self, const float* __restrict__ W_rel,
    unsigned short* __restrict__ Wt)
{
    const int id = blockIdx.x * 256 + threadIdx.x;  // 65536
    const int m = id >> 14, rem = id & 16383;
    const int k = rem >> 7, n = rem & 127;
    const float* src = (m == 0) ? W_self : (W_rel + (size_t)(m - 1) * 16384);
    Wt[m * 16384 + n * 128 + k] = f2bf(src[k * 128 + n]);
}

// ---------------------------------------------------------------------------
// MFMA GEMM: mat 0 -> z = x@W_self (fp32); mat 1..3 -> y_r = x@W_r (bf16)
// ---------------------------------------------------------------------------
__global__ __launch_bounds__(256) void gemm_kernel(
    const unsigned short* __restrict__ xb,
    const unsigned short* __restrict__ Wt,
    float* __restrict__ z,
    unsigned short* __restrict__ y)
{
    __shared__ unsigned short As[64 * 136];
    __shared__ unsigned short Bs[128 * 136];
    const int tid = threadIdx.x;
    const int m0  = blockIdx.x * 64;
    const int mat = blockIdx.y;

    #pragma unroll
    for (int i = 0; i < 4; ++i) {
        int c = tid + i * 256;
        int row = c >> 4, ch = c & 15;
        int gr = m0 + row;
        uint4 v = make_uint4(0u, 0u, 0u, 0u);
        if (gr < NN) v = *(const uint4*)(xb + (size_t)gr * 128 + ch * 8);
        *(uint4*)&As[row * 136 + ch * 8] = v;
    }
    {
        const unsigned short* wsrc = Wt + (size_t)mat * 16384;
        #pragma unroll
        for (int i = 0; i < 8; ++i) {
            int c = tid + i * 256;
            int n = c >> 4, ch = c & 15;
            *(uint4*)&Bs[n * 136 + ch * 8] = *(const uint4*)(wsrc + n * 128 + ch * 8);
        }
    }
    __syncthreads();

    const int wave = tid >> 6;
    const int lane = tid & 63;
    const int lm = lane & 15;
    const int lq = lane >> 4;

    short8 af[4];
    #pragma unroll
    for (int ks = 0; ks < 4; ++ks)
        af[ks] = *(const short8*)&As[(wave * 16 + lm) * 136 + ks * 32 + lq * 8];

    f32x4 acc[8];
    #pragma unroll
    for (int n = 0; n < 8; ++n) acc[n] = (f32x4){0.f, 0.f, 0.f, 0.f};

    #pragma unroll
    for (int n = 0; n < 8; ++n) {
        #pragma unroll
        for (int ks = 0; ks < 4; ++ks) {
            short8 bf = *(const short8*)&Bs[(n * 16 + lm) * 136 + ks * 32 + lq * 8];
            acc[n] = __builtin_amdgcn_mfma_f32_16x16x32_bf16(af[ks], bf, acc[n], 0, 0, 0);
        }
    }

    if (mat == 0) {
        #pragma unroll
        for (int n = 0; n < 8; ++n)
            #pragma unroll
            for (int j = 0; j < 4; ++j) {
                int gr = m0 + wave * 16 + lq * 4 + j;
                if (gr < NN) z[(size_t)gr * 128 + n * 16 + lm] = acc[n][j];
            }
    } else {
        unsigned short* yp = y + (size_t)(mat - 1) * NN * 128;
        #pragma unroll
        for (int n = 0; n < 8; ++n)
            #pragma unroll
            for (int j = 0; j < 4; ++j) {
                int gr = m0 + wave * 16 + lq * 4 + j;
                if (gr < NN) yp[(size_t)gr * 128 + n * 16 + lm] = f2bf(acc[n][j]);
            }
    }
}

// ---------------------------------------------------------------------------
// CSR build: histogram -> scan -> fill. key = r*NN + dst.
// ---------------------------------------------------------------------------
__global__ __launch_bounds__(256) void hist_kernel(
    const int* __restrict__ ei, unsigned* __restrict__ cur)
{
    const int eid = blockIdx.x * 256 + threadIdx.x;
    if (eid < NEDGE) {
        const int dst = ei[2 * eid + 1];
        const int r = (eid >= 2 * NE) ? 2 : (eid >= NE ? 1 : 0);
        atomicAdd(&cur[r * NN + dst], 1u);
    }
}

// per-block exclusive scan of 1024 counts; block total -> bsum
__global__ __launch_bounds__(256) void scan1_kernel(
    const unsigned* __restrict__ cnt, unsigned* __restrict__ offs,
    unsigned* __restrict__ bsum)
{
    __shared__ unsigned wtot[4];
    const int tid = threadIdx.x, lane = tid & 63, wv = tid >> 6;
    const int base = blockIdx.x * 1024 + tid * 4;
    unsigned c[4];
    #pragma unroll
    for (int j = 0; j < 4; ++j) c[j] = (base + j < NKEY) ? cnt[base + j] : 0u;
    const unsigned ts = c[0] + c[1] + c[2] + c[3];
    unsigned incl = ts;
    #pragma unroll
    for (int d = 1; d < 64; d <<= 1) {
        unsigned v = __shfl_up(incl, d, 64);
        if (lane >= d) incl += v;
    }
    if (lane == 63) wtot[wv] = incl;
    __syncthreads();
    unsigned woff = 0;
    for (int p = 0; p < 4; ++p) if (p < wv) woff += wtot[p];
    unsigned run = woff + incl - ts;
    #pragma unroll
    for (int j = 0; j < 4; ++j) {
        if (base + j < NKEY) offs[base + j] = run;
        run += c[j];
    }
    if (tid == 255) bsum[blockIdx.x] = woff + incl;
}

// one wave scans NB1 block sums (5 per lane)
__global__ void scan2_kernel(unsigned* __restrict__ bsum)
{
    const int lane = threadIdx.x;   // 64 threads
    unsigned v[5], s = 0;
    const int base = lane * 5;
    #pragma unroll
    for (int j = 0; j < 5; ++j) {
        v[j] = (base + j < NB1) ? bsum[base + j] : 0u;
        s += v[j];
    }
    unsigned incl = s;
    #pragma unroll
    for (int d = 1; d < 64; d <<= 1) {
        unsigned t = __shfl_up(incl, d, 64);
        if (lane >= d) incl += t;
    }
    unsigned run = incl - s;
    #pragma unroll
    for (int j = 0; j < 5; ++j) {
        if (base + j < NB1) bsum[base + j] = run;
        run += v[j];
    }
}

// finalize offs, init cursor copy, write sentinel
__global__ __launch_bounds__(256) void scan3_kernel(
    unsigned* __restrict__ offs, unsigned* __restrict__ cur,
    const unsigned* __restrict__ bsum)
{
    const int base = blockIdx.x * 1024 + threadIdx.x * 4;
    const unsigned add = bsum[blockIdx.x];
    #pragma unroll
    for (int j = 0; j < 4; ++j) {
        if (base + j < NKEY) {
            unsigned v = offs[base + j] + add;
            offs[base + j] = v;
            cur[base + j]  = v;
        }
    }
    if (blockIdx.x == 0 && threadIdx.x == 0) offs[NKEY] = NEDGE;
}

__global__ __launch_bounds__(256) void fill_kernel(
    const int* __restrict__ ei, unsigned* __restrict__ cur,
    uint2* __restrict__ elist)
{
    const int eid = blockIdx.x * 256 + threadIdx.x;
    if (eid < NEDGE) {
        const int src = ei[2 * eid + 0];
        const int dst = ei[2 * eid + 1];
        const int r = (eid >= 2 * NE) ? 2 : (eid >= NE ? 1 : 0);
        const unsigned pos = atomicAdd(&cur[r * NN + dst], 1u);
        elist[pos] = make_uint2((unsigned)src, (unsigned)eid);
    }
}

// ---------------------------------------------------------------------------
// Aggregate: one wave per dst row.
//   out[dst] = relu( z[dst] + sum_{r,e in CSR} y_r[src] + (sum ea_r) @ We_r + b )
// lane covers cols {2*lane, 2*lane+1}; edge_attr accumulated 4x-replicated
// (k = lane&15), folded through LDS after the edge loop.
// ---------------------------------------------------------------------------
__global__ __launch_bounds__(256) void aggregate_kernel(
    const float* __restrict__ z,
    const unsigned short* __restrict__ y,
    const float* __restrict__ edge_attr,
    const float* __restrict__ We,
    const float* __restrict__ b,
    const unsigned* __restrict__ offs,
    const uint2* __restrict__ elist,
    float* __restrict__ out)
{
    __shared__ float WeS[NR * 16 * 128];   // 24 KB
    __shared__ float eaS[4][NR][16];
    const int tid = threadIdx.x;
    for (int i = tid; i < NR * 16 * 128 / 4; i += 256)
        ((float4*)WeS)[i] = ((const float4*)We)[i];
    __syncthreads();

    const int wv = tid >> 6, lane = tid & 63;
    const int dst = blockIdx.x * 4 + wv;          // grid = 25000, exact
    const int col = 2 * lane;
    const int k16 = lane & 15;

    const float2 zv = *(const float2*)(z + (size_t)dst * 128 + col);
    float acc0 = zv.x, acc1 = zv.y;
    float ea[NR];

    #pragma unroll
    for (int r = 0; r < NR; ++r) {
        const unsigned s = offs[r * NN + dst];
        const unsigned e = offs[r * NN + dst + 1];
        const unsigned short* yr = y + (size_t)r * NN * 128;
        float eac = 0.f;
        for (unsigned i = s; i < e; ++i) {
            const uint2 p = elist[i];
            const unsigned v = *(const unsigned*)(yr + (size_t)p.x * 128 + col);
            acc0 += __uint_as_float(v << 16);
            acc1 += __uint_as_float(v & 0xffff0000u);
            eac  += edge_attr[(size_t)p.y * 16 + k16];
        }
        ea[r] = eac;
    }

    if (lane < 16) {
        eaS[wv][0][lane] = ea[0];
        eaS[wv][1][lane] = ea[1];
        eaS[wv][2][lane] = ea[2];
    }
    __syncthreads();

    #pragma unroll
    for (int r = 0; r < NR; ++r)
        #pragma unroll
        for (int k = 0; k < 16; ++k) {
            const float evk = eaS[wv][r][k];
            acc0 = fmaf(evk, WeS[(r * 16 + k) * 128 + col], acc0);
            acc1 = fmaf(evk, WeS[(r * 16 + k) * 128 + col + 1], acc1);
        }

    const float2 bv = *(const float2*)(b + col);
    float2 o;
    o.x = fmaxf(acc0 + bv.x, 0.f);
    o.y = fmaxf(acc1 + bv.y, 0.f);
    *(float2*)(out + (size_t)dst * 128 + col) = o;
}

extern "C" void kernel_launch(void* const* d_in, const int* in_sizes, int n_in,
                              void* d_out, int out_size, void* d_ws, size_t ws_size,
                              hipStream_t stream)
{
    const float* x         = (const float*)d_in[0];
    const float* edge_attr = (const float*)d_in[1];
    const float* W_rel     = (const float*)d_in[2];
    const float* We_rel    = (const float*)d_in[3];
    const float* W_self    = (const float*)d_in[4];
    const float* b         = (const float*)d_in[5];
    const int*   edge_index= (const int*)d_in[6];
    float* out = (float*)d_out;

    // ws layout (bytes)
    char* wsb = (char*)d_ws;
    float*          z    = (float*)wsb;                              //  51,200,000
    unsigned short* xb   = (unsigned short*)(wsb + 51200000);        //  25,600,000
    unsigned short* y    = (unsigned short*)(wsb + 76800000);        //  76,800,000
    unsigned short* Wt   = (unsigned short*)(wsb + 153600000);       //     131,072
    unsigned*       cur  = (unsigned*)(wsb + 153731072);             //   1,200,000
    unsigned*       offs = (unsigned*)(wsb + 154931072);             //   1,200,004
    unsigned*       bsum = (unsigned*)(wsb + 156131080);             //       1,280
    uint2*          elist= (uint2*)(wsb + 156132360);                //   4,800,000

    // dense chain
    conv_x_kernel<<<NN * DN / 4 / 256, 256, 0, stream>>>(x, xb);
    conv_w_kernel<<<256, 256, 0, stream>>>(W_self, W_rel, Wt);
    dim3 ggrid((NN + 63) / 64, 4);
    gemm_kernel<<<ggrid, 256, 0, stream>>>(xb, Wt, z, y);

    // CSR build
    hipMemsetAsync(cur, 0, NKEY * sizeof(unsigned), stream);
    const int eblocks = (NEDGE + 255) / 256;
    hist_kernel <<<eblocks, 256, 0, stream>>>(edge_index, cur);
    scan1_kernel<<<NB1, 256, 0, stream>>>(cur, offs, bsum);
    scan2_kernel<<<1, 64, 0, stream>>>(bsum);
    scan3_kernel<<<NB1, 256, 0, stream>>>(offs, cur, bsum);
    fill_kernel <<<eblocks, 256, 0, stream>>>(edge_index, cur, elist);

    // aggregate + epilogue
    aggregate_kernel<<<NN / 4, 256, 0, stream>>>(z, y, edge_attr, We_rel, b,
                                                 offs, elist, out);
}

// Round 5
// 367.827 us; speedup vs baseline: 6.0874x; 1.1840x over previous
//
#include <hip/hip_runtime.h>

#define NN 100000
#define NE 200000
#define DN 128
#define DE 16
#define NR 3
#define NEDGE (NR * NE)         // 600000
#define NB1 98                  // scan1 blocks: 1024 elems each >= NN

typedef __attribute__((ext_vector_type(8))) short short8;
typedef __attribute__((ext_vector_type(4))) float f32x4;

__device__ __forceinline__ unsigned short f2bf(float f) {
    unsigned int u = __float_as_uint(f);
    u = (u + 0x7fffu + ((u >> 16) & 1u)) >> 16;   // RNE
    return (unsigned short)u;
}

// ---------------------------------------------------------------------------
// Wt[m][n][k] = bf16(W_m[k][n]) (n-major for MFMA B-fragments). m=0 self, 1..3 rel
// ---------------------------------------------------------------------------
__global__ __launch_bounds__(256) void conv_w_kernel(
    const float* __restrict__ W_self, const float* __restrict__ W_rel,
    unsigned short* __restrict__ Wt)
{
    const int id = blockIdx.x * 256 + threadIdx.x;  // 65536
    const int m = id >> 14, rem = id & 16383;
    const int k = rem >> 7, n = rem & 127;
    const float* src = (m == 0) ? W_self : (W_rel + (size_t)(m - 1) * 16384);
    Wt[m * 16384 + n * 128 + k] = f2bf(src[k * 128 + n]);
}

// ---------------------------------------------------------------------------
// MFMA GEMM, conv_x fused: stage x tile fp32->bf16 once, loop 4 weight mats.
//   mat 0 -> zb = bf16(x@W_self); mat 1..3 -> y_r = bf16(x@W_r)
// Block: 256 thr = 64 rows x 128 cols, K=128 single stage.
// 64 rows x 128 f32 = 2048 float4 chunks -> i < 8  (ROUND-4 BUG: was i < 4)
// ---------------------------------------------------------------------------
__global__ __launch_bounds__(256) void gemm_kernel(
    const float* __restrict__ x,
    const unsigned short* __restrict__ Wt,
    unsigned short* __restrict__ zb,
    unsigned short* __restrict__ y)
{
    __shared__ unsigned short As[64 * 136];
    __shared__ unsigned short Bs[128 * 136];
    const int tid = threadIdx.x;
    const int m0  = blockIdx.x * 64;

    // stage A: read fp32, convert to bf16 in LDS — 2048 float4 chunks
    #pragma unroll
    for (int i = 0; i < 8; ++i) {
        int c = tid + i * 256;             // 0..2047 float4 chunks
        int row = c >> 5, fc = c & 31;     // 32 float4 per row
        int gr = m0 + row;
        float4 v = make_float4(0.f, 0.f, 0.f, 0.f);
        if (gr < NN) v = *(const float4*)(x + (size_t)gr * 128 + fc * 4);
        ushort4 o;
        o.x = f2bf(v.x); o.y = f2bf(v.y); o.z = f2bf(v.z); o.w = f2bf(v.w);
        *(ushort4*)&As[row * 136 + fc * 4] = o;
    }
    __syncthreads();

    const int wave = tid >> 6;
    const int lane = tid & 63;
    const int lm = lane & 15;
    const int lq = lane >> 4;

    short8 af[4];
    #pragma unroll
    for (int ks = 0; ks < 4; ++ks)
        af[ks] = *(const short8*)&As[(wave * 16 + lm) * 136 + ks * 32 + lq * 8];

    for (int mat = 0; mat < 4; ++mat) {
        const unsigned short* wsrc = Wt + (size_t)mat * 16384;
        #pragma unroll
        for (int i = 0; i < 8; ++i) {
            int c = tid + i * 256;
            int n = c >> 4, ch = c & 15;
            *(uint4*)&Bs[n * 136 + ch * 8] = *(const uint4*)(wsrc + n * 128 + ch * 8);
        }
        __syncthreads();

        f32x4 acc[8];
        #pragma unroll
        for (int n = 0; n < 8; ++n) acc[n] = (f32x4){0.f, 0.f, 0.f, 0.f};
        #pragma unroll
        for (int n = 0; n < 8; ++n)
            #pragma unroll
            for (int ks = 0; ks < 4; ++ks) {
                short8 bf = *(const short8*)&Bs[(n * 16 + lm) * 136 + ks * 32 + lq * 8];
                acc[n] = __builtin_amdgcn_mfma_f32_16x16x32_bf16(af[ks], bf, acc[n], 0, 0, 0);
            }

        unsigned short* outp = (mat == 0) ? zb : (y + (size_t)(mat - 1) * NN * 128);
        #pragma unroll
        for (int n = 0; n < 8; ++n)
            #pragma unroll
            for (int j = 0; j < 4; ++j) {
                int gr = m0 + wave * 16 + lq * 4 + j;
                if (gr < NN) outp[(size_t)gr * 128 + n * 16 + lm] = f2bf(acc[n][j]);
            }
        __syncthreads();   // Bs reused next mat
    }
}

// ---------------------------------------------------------------------------
// CSR build keyed by dst only.
// ---------------------------------------------------------------------------
__global__ __launch_bounds__(256) void hist_kernel(
    const int* __restrict__ ei, unsigned* __restrict__ cur)
{
    const int eid = blockIdx.x * 256 + threadIdx.x;
    if (eid < NEDGE) atomicAdd(&cur[ei[2 * eid + 1]], 1u);
}

__global__ __launch_bounds__(256) void scan1_kernel(
    const unsigned* __restrict__ cnt, unsigned* __restrict__ offs,
    unsigned* __restrict__ bsum)
{
    __shared__ unsigned wtot[4];
    const int tid = threadIdx.x, lane = tid & 63, wv = tid >> 6;
    const int base = blockIdx.x * 1024 + tid * 4;
    unsigned c[4];
    #pragma unroll
    for (int j = 0; j < 4; ++j) c[j] = (base + j < NN) ? cnt[base + j] : 0u;
    const unsigned ts = c[0] + c[1] + c[2] + c[3];
    unsigned incl = ts;
    #pragma unroll
    for (int d = 1; d < 64; d <<= 1) {
        unsigned v = __shfl_up(incl, d, 64);
        if (lane >= d) incl += v;
    }
    if (lane == 63) wtot[wv] = incl;
    __syncthreads();
    unsigned woff = 0;
    for (int p = 0; p < 4; ++p) if (p < wv) woff += wtot[p];
    unsigned run = woff + incl - ts;
    #pragma unroll
    for (int j = 0; j < 4; ++j) {
        if (base + j < NN) offs[base + j] = run;
        run += c[j];
    }
    if (tid == 255) bsum[blockIdx.x] = woff + incl;
}

__global__ void scan2_kernel(unsigned* __restrict__ bsum)
{
    const int lane = threadIdx.x;   // 64
    unsigned v[2], s = 0;
    const int base = lane * 2;
    #pragma unroll
    for (int j = 0; j < 2; ++j) {
        v[j] = (base + j < NB1) ? bsum[base + j] : 0u;
        s += v[j];
    }
    unsigned incl = s;
    #pragma unroll
    for (int d = 1; d < 64; d <<= 1) {
        unsigned t = __shfl_up(incl, d, 64);
        if (lane >= d) incl += t;
    }
    unsigned run = incl - s;
    #pragma unroll
    for (int j = 0; j < 2; ++j) {
        if (base + j < NB1) bsum[base + j] = run;
        run += v[j];
    }
}

__global__ __launch_bounds__(256) void scan3_kernel(
    unsigned* __restrict__ offs, unsigned* __restrict__ cur,
    const unsigned* __restrict__ bsum)
{
    const int base = blockIdx.x * 1024 + threadIdx.x * 4;
    const unsigned add = bsum[blockIdx.x];
    #pragma unroll
    for (int j = 0; j < 4; ++j) {
        if (base + j < NN) {
            unsigned v = offs[base + j] + add;
            offs[base + j] = v;
            cur[base + j]  = v;
        }
    }
    if (blockIdx.x == 0 && threadIdx.x == 0) offs[NN] = NEDGE;
}

__global__ __launch_bounds__(256) void fill_kernel(
    const int* __restrict__ ei, unsigned* __restrict__ cur,
    uint2* __restrict__ elist)
{
    const int eid = blockIdx.x * 256 + threadIdx.x;
    if (eid < NEDGE) {
        const unsigned src = (unsigned)ei[2 * eid + 0];
        const int dst = ei[2 * eid + 1];
        const unsigned r = (eid >= 2 * NE) ? 2u : (eid >= NE ? 1u : 0u);
        const unsigned pos = atomicAdd(&cur[dst], 1u);
        elist[pos] = make_uint2(r * NN + src, (unsigned)eid);   // x = y-row index
    }
}

// ---------------------------------------------------------------------------
// Aggregate: one wave per dst, single CSR segment (all relations).
//   out[dst] = relu( z[dst] + sum_e y[row_e] + sum_r ea_r @ We_r + b )
// Edge loop unrolled 4x -> 4 independent elist->y chains in flight.
// ---------------------------------------------------------------------------
__global__ __launch_bounds__(256) void aggregate_kernel(
    const unsigned short* __restrict__ zb,
    const unsigned short* __restrict__ y,      // [3*NN][128] bf16
    const float* __restrict__ edge_attr,       // [NEDGE][16]
    const float* __restrict__ We,              // [3][16][128]
    const float* __restrict__ b,
    const unsigned* __restrict__ offs,         // [NN+1]
    const uint2* __restrict__ elist,
    float* __restrict__ out)
{
    __shared__ float WeS[NR * 16 * 128];   // 24 KB
    __shared__ float eaS[4][NR][16];
    const int tid = threadIdx.x;
    for (int i = tid; i < NR * 16 * 128 / 4; i += 256)
        ((float4*)WeS)[i] = ((const float4*)We)[i];

    const int wv = tid >> 6, lane = tid & 63;
    const int dst = blockIdx.x * 4 + wv;          // grid 25000, exact
    const int col = 2 * lane;
    const int k16 = lane & 15;

    const unsigned s = offs[dst];
    const unsigned e = offs[dst + 1];

    const unsigned zv = *(const unsigned*)(zb + (size_t)dst * 128 + col);
    float acc0 = __uint_as_float(zv << 16);
    float acc1 = __uint_as_float(zv & 0xffff0000u);
    float ea0 = 0.f, ea1 = 0.f, ea2 = 0.f;

    unsigned i = s;
    for (; i + 4 <= e; i += 4) {
        const uint2 p0 = elist[i],     p1 = elist[i + 1];
        const uint2 p2 = elist[i + 2], p3 = elist[i + 3];
        const unsigned v0 = *(const unsigned*)(y + (size_t)p0.x * 128 + col);
        const unsigned v1 = *(const unsigned*)(y + (size_t)p1.x * 128 + col);
        const unsigned v2 = *(const unsigned*)(y + (size_t)p2.x * 128 + col);
        const unsigned v3 = *(const unsigned*)(y + (size_t)p3.x * 128 + col);
        const float a0 = edge_attr[(size_t)p0.y * 16 + k16];
        const float a1 = edge_attr[(size_t)p1.y * 16 + k16];
        const float a2 = edge_attr[(size_t)p2.y * 16 + k16];
        const float a3 = edge_attr[(size_t)p3.y * 16 + k16];
        acc0 += __uint_as_float(v0 << 16) + __uint_as_float(v1 << 16)
              + __uint_as_float(v2 << 16) + __uint_as_float(v3 << 16);
        acc1 += __uint_as_float(v0 & 0xffff0000u) + __uint_as_float(v1 & 0xffff0000u)
              + __uint_as_float(v2 & 0xffff0000u) + __uint_as_float(v3 & 0xffff0000u);
        ea0 += ((p0.y < NE) ? a0 : 0.f) + ((p1.y < NE) ? a1 : 0.f)
             + ((p2.y < NE) ? a2 : 0.f) + ((p3.y < NE) ? a3 : 0.f);
        ea1 += ((p0.y >= NE && p0.y < 2u * NE) ? a0 : 0.f)
             + ((p1.y >= NE && p1.y < 2u * NE) ? a1 : 0.f)
             + ((p2.y >= NE && p2.y < 2u * NE) ? a2 : 0.f)
             + ((p3.y >= NE && p3.y < 2u * NE) ? a3 : 0.f);
        ea2 += ((p0.y >= 2u * NE) ? a0 : 0.f) + ((p1.y >= 2u * NE) ? a1 : 0.f)
             + ((p2.y >= 2u * NE) ? a2 : 0.f) + ((p3.y >= 2u * NE) ? a3 : 0.f);
    }
    for (; i < e; ++i) {
        const uint2 p = elist[i];
        const unsigned v = *(const unsigned*)(y + (size_t)p.x * 128 + col);
        const float a = edge_attr[(size_t)p.y * 16 + k16];
        acc0 += __uint_as_float(v << 16);
        acc1 += __uint_as_float(v & 0xffff0000u);
        ea0 += (p.y < NE) ? a : 0.f;
        ea1 += (p.y >= NE && p.y < 2u * NE) ? a : 0.f;
        ea2 += (p.y >= 2u * NE) ? a : 0.f;
    }

    __syncthreads();          // WeS staged; also orders eaS write below
    if (lane < 16) {
        eaS[wv][0][lane] = ea0;
        eaS[wv][1][lane] = ea1;
        eaS[wv][2][lane] = ea2;
    }
    __syncthreads();

    #pragma unroll
    for (int r = 0; r < NR; ++r)
        #pragma unroll
        for (int k = 0; k < 16; ++k) {
            const float evk = eaS[wv][r][k];
            acc0 = fmaf(evk, WeS[(r * 16 + k) * 128 + col], acc0);
            acc1 = fmaf(evk, WeS[(r * 16 + k) * 128 + col + 1], acc1);
        }

    const float2 bv = *(const float2*)(b + col);
    float2 o;
    o.x = fmaxf(acc0 + bv.x, 0.f);
    o.y = fmaxf(acc1 + bv.y, 0.f);
    *(float2*)(out + (size_t)dst * 128 + col) = o;
}

extern "C" void kernel_launch(void* const* d_in, const int* in_sizes, int n_in,
                              void* d_out, int out_size, void* d_ws, size_t ws_size,
                              hipStream_t stream)
{
    const float* x         = (const float*)d_in[0];
    const float* edge_attr = (const float*)d_in[1];
    const float* W_rel     = (const float*)d_in[2];
    const float* We_rel    = (const float*)d_in[3];
    const float* W_self    = (const float*)d_in[4];
    const float* b         = (const float*)d_in[5];
    const int*   edge_index= (const int*)d_in[6];
    float* out = (float*)d_out;

    // ws layout (bytes)
    char* wsb = (char*)d_ws;
    unsigned short* zb   = (unsigned short*)wsb;                     //  25,600,000
    unsigned short* y    = (unsigned short*)(wsb + 25600000);        //  76,800,000
    unsigned short* Wt   = (unsigned short*)(wsb + 102400000);       //     131,072
    unsigned*       cur  = (unsigned*)(wsb + 102531072);             //     400,000
    unsigned*       offs = (unsigned*)(wsb + 102931072);             //     400,004
    unsigned*       bsum = (unsigned*)(wsb + 103331080);             //         512
    uint2*          elist= (uint2*)(wsb + 103331592);                //   4,800,000

    conv_w_kernel<<<256, 256, 0, stream>>>(W_self, W_rel, Wt);
    gemm_kernel<<<(NN + 63) / 64, 256, 0, stream>>>(x, Wt, zb, y);

    hipMemsetAsync(cur, 0, NN * sizeof(unsigned), stream);
    const int eblocks = (NEDGE + 255) / 256;
    hist_kernel <<<eblocks, 256, 0, stream>>>(edge_index, cur);
    scan1_kernel<<<NB1, 256, 0, stream>>>(cur, offs, bsum);
    scan2_kernel<<<1, 64, 0, stream>>>(bsum);
    scan3_kernel<<<NB1, 256, 0, stream>>>(offs, cur, bsum);
    fill_kernel <<<eblocks, 256, 0, stream>>>(edge_index, cur, elist);

    aggregate_kernel<<<NN / 4, 256, 0, stream>>>(zb, y, edge_attr, We_rel, b,
                                                 offs, elist, out);
}